// Round 1
// baseline (144.208 us; speedup 1.0000x reference)
//
#include <hip/hip_runtime.h>

#define NL2E (-1.4426950408889634f)

__device__ __forceinline__ float rl(float v, int lane) {
    return __int_as_float(__builtin_amdgcn_readlane(__float_as_int(v), lane));
}

__global__ __launch_bounds__(64) void leaf_integ_kernel(
    const float* __restrict__ S_conv, const float* __restrict__ up_mu_Z,
    const float* __restrict__ noise, const float* __restrict__ W_sub,
    const float* __restrict__ theta_syn, const float* __restrict__ theta_spike,
    const float* __restrict__ W_spike, const float* __restrict__ tau_hist,
    const float* __restrict__ K_hist, const float* __restrict__ delta_hist,
    float* __restrict__ out)
{
    const int SUB = 1024;
    int bid = blockIdx.x;
    // XCD-locality swizzle: consecutive s on same XCD so output lines merge in L2
    int s = ((bid & 7) << 7) + (bid >> 3);
    int l = threadIdx.x;

    __shared__ float lds_rev[128];

    // per-unit params (wave-uniform)
    float thsyn = theta_syn[s];
    float thspk = theta_spike[s];
    float wsub  = W_sub[s];
    float wspk  = W_spike[s];
    float delta = delta_hist[s];

    // history kernel for lag = lane, pre-scaled by -log2(e)
    float tt = fmaxf((float)l - delta, 0.0f);
    float kern = 0.0f;
    #pragma unroll
    for (int b = 0; b < 4; ++b) {
        float rtau = __expf(-tau_hist[b]);   // 1/exp(tau_hist[b])
        float ttau = tt * rtau;
        kern += ttau * __expf(-ttau) * K_hist[s * 4 + b];
    }
    float kvs = NL2E * kern;
    // lds_rev[a] = kern_scaled[(63 - a) & 63], doubled so per-phase read needs no mod
    lds_rev[63 - l]  = kvs;
    lds_rev[127 - l] = kvs;
    __syncthreads();

    const float* krow = &lds_rev[64 - l];  // krow[j] = scaled kern[(l-1-j)&63]

    float thsynS = NL2E * thsyn;
    float c1 = NL2E * 0.5f * wspk;

    // prologue loads: block 0 (for A init + pre), block 1 s (reset source)
    float s0raw = S_conv[(size_t)l * SUB + s];
    float s1raw = S_conv[(size_t)(64 + l) * SUB + s];
    float up0   = up_mu_Z[(size_t)l * SUB + s];
    float n0    = noise[(size_t)l * SUB + s];

    // A: scaled accumulator; lane l holds next timestep t' == l (mod 64)
    float A    = fmaf(s0raw, NL2E, thsynS);
    float sA   = fmaf(s1raw, NL2E, thsynS);
    float preA = NL2E * (fmaf(0.5f, up0, 0.5f * thspk) + n0);
    float upA  = up0;

    float ab = rl(A, 0);
    float pb = rl(preA, 0);

    float xcap = 0.0f, zcap = 0.0f;

    float* Yo = out;
    float* Zo = out + 4194304;
    float* Mo = out + 8388608;
    float* Do = out + 12582912;

    for (int m = 0; m < 64; ++m) {
        int t0 = m * 64;
        // prefetch next blocks (issue now, consumed at block end; clamped at tail)
        int tP = min(t0 + 128 + l, 4095);
        int tQ = min(t0 + 64 + l, 4095);
        float sB  = S_conv[(size_t)tP * SUB + s];
        float upB = up_mu_Z[(size_t)tQ * SUB + s];
        float nB  = noise[(size_t)tQ * SUB + s];

        #pragma unroll
        for (int j = 0; j < 64; ++j) {
            // prefetch broadcasts for next phase BEFORE this phase's A-update:
            // lane (j+1)'s A is complete (its lag-0 tap is identically 0)
            float ab_nx = rl(A, (j + 1) & 63);
            float pb_nx = (j < 63) ? rl(preA, j + 1) : pb;

            // chain: X_out = sigmoid(X_in) with pre-scaled inputs
            float e1 = __builtin_amdgcn_exp2f(ab);
            float kv = krow[j];                      // ds_read, off-chain
            float xo = __builtin_amdgcn_rcpf(1.0f + e1);
            float vv = fmaf(xo, c1, pb);
            float e2 = __builtin_amdgcn_exp2f(vv);
            float z  = __builtin_amdgcn_rcpf(1.0f + e2);

            bool sel = (l == j);
            xcap = sel ? xo : xcap;
            zcap = sel ? z  : zcap;
            float base = sel ? sA : A;               // lane j resets to s_{t+64}+theta
            A = fmaf(kv, z, base);

            ab = ab_nx;
            pb = pb_nx;
        }

        // block-end: compute + store outputs vectorized (lane l holds phase l)
        float down = fmaf(xcap, wspk, thspk);
        float Yv   = xcap * wsub;
        float mu   = 0.5f * (upA + down);
        size_t o = (size_t)(t0 + l) * SUB + s;
        Yo[o] = Yv; Zo[o] = zcap; Mo[o] = mu; Do[o] = down;

        // swap double-buffered inputs
        sA   = fmaf(sB, NL2E, thsynS);
        preA = NL2E * (fmaf(0.5f, upB, 0.5f * thspk) + nB);
        upA  = upB;
        pb   = rl(preA, 0);
    }
}

extern "C" void kernel_launch(void* const* d_in, const int* in_sizes, int n_in,
                              void* d_out, int out_size, void* d_ws, size_t ws_size,
                              hipStream_t stream) {
    const float* S_conv     = (const float*)d_in[0];
    const float* up_mu_Z    = (const float*)d_in[1];
    const float* noise      = (const float*)d_in[2];
    const float* W_sub      = (const float*)d_in[3];
    const float* theta_syn  = (const float*)d_in[4];
    const float* theta_spike= (const float*)d_in[5];
    const float* W_spike    = (const float*)d_in[6];
    const float* tau_hist   = (const float*)d_in[7];
    const float* K_hist     = (const float*)d_in[8];
    const float* delta_hist = (const float*)d_in[9];
    float* out = (float*)d_out;

    leaf_integ_kernel<<<dim3(1024), dim3(64), 0, stream>>>(
        S_conv, up_mu_Z, noise, W_sub, theta_syn, theta_spike, W_spike,
        tau_hist, K_hist, delta_hist, out);
}